// Round 7
// baseline (324.588 us; speedup 1.0000x reference)
//
#include <hip/hip_runtime.h>
#include <cmath>

#define B_    2
#define T_    512
#define C_    1024
#define E_    8
#define NTOK  1024
#define NPAIR 2048
#define AH_   1024
#define NH_   8
#define HS_   128

typedef unsigned short u16;
typedef __attribute__((ext_vector_type(8))) short bf16x8;
typedef __attribute__((ext_vector_type(4))) float f32x4;

__device__ __forceinline__ u16 f2bf(float f) {
    union { float f; unsigned u; } v; v.f = f;
    unsigned r = v.u + 0x7fff + ((v.u >> 16) & 1);   // RNE
    return (u16)(r >> 16);
}

__device__ __forceinline__ void gload_lds16(const void* g, void* l) {
    __builtin_amdgcn_global_load_lds(
        (const __attribute__((address_space(1))) void*)g,
        (__attribute__((address_space(3))) void*)l, 16, 0, 0);
}

// ---------------- kernel 1: gate logits, top-2, x->bf16 (NO global atomics) ----------------
__global__ __launch_bounds__(64) void gate_kernel(
    const float* __restrict__ x, const float* __restrict__ Wg,
    u16* __restrict__ xb, float* __restrict__ gates,
    float* __restrict__ probs, int* __restrict__ eass)
{
    int token = blockIdx.x;
    int lane  = threadIdx.x;
    const float* xr = x + (size_t)token * C_;
    u16* xbr = xb + (size_t)token * C_;
    float acc[E_];
#pragma unroll
    for (int e = 0; e < E_; e++) acc[e] = 0.f;
    for (int c = lane; c < C_; c += 64) {
        float xv = xr[c];
        xbr[c] = f2bf(xv);
        const float* wr = Wg + c * E_;
#pragma unroll
        for (int e = 0; e < E_; e++) acc[e] += xv * wr[e];
    }
#pragma unroll
    for (int e = 0; e < E_; e++) {
        float v = acc[e];
        v += __shfl_xor(v, 32); v += __shfl_xor(v, 16); v += __shfl_xor(v, 8);
        v += __shfl_xor(v, 4);  v += __shfl_xor(v, 2);  v += __shfl_xor(v, 1);
        acc[e] = v;
    }
    if (lane == 0) {
        int i0 = 0; float v0 = acc[0];
        for (int e = 1; e < E_; e++) if (acc[e] > v0) { v0 = acc[e]; i0 = e; }
        int i1 = -1; float v1 = -3.4e38f;
        for (int e = 0; e < E_; e++) if (e != i0 && acc[e] > v1) { v1 = acc[e]; i1 = e; }
        float e1  = __expf(v1 - v0);
        float inv = 1.f / (1.f + e1);
        gates[token * 2 + 0] = inv;
        gates[token * 2 + 1] = e1 * inv;
        float s = 0.f; float pe[E_];
        for (int e = 0; e < E_; e++) { pe[e] = __expf(acc[e] - v0); s += pe[e]; }
        float sinv = 1.f / s;
        for (int e = 0; e < E_; e++) probs[token * E_ + e] = pe[e] * sinv;
        eass[token * 2 + 0] = i0;
        eass[token * 2 + 1] = i1;
    }
}

// ---------------- kernel 1b: aux-loss reduce + bucket build (single block) ----------------
__global__ __launch_bounds__(256) void route_kernel(
    const float* __restrict__ probs, const int* __restrict__ eass,
    const float* __restrict__ bk, const float* __restrict__ bv,
    int* __restrict__ bucket_cnt, int* __restrict__ buckets,
    float* __restrict__ bkv, float* __restrict__ aux_out)
{
    __shared__ float red[256][17];
    __shared__ int lcnt[E_];
    int tid = threadIdx.x;
    for (int i = tid; i < 1024; i += 256) {
        bkv[i] = bk[i];
        bkv[i + 1024] = bv[i];
    }
    float ps[E_], fc[E_];
#pragma unroll
    for (int e = 0; e < E_; e++) { ps[e] = 0.f; fc[e] = 0.f; }
    for (int k = 0; k < 4; k++) {
        int row = tid + k * 256;
#pragma unroll
        for (int e = 0; e < E_; e++) ps[e] += probs[row * E_ + e];
    }
    for (int k = 0; k < 8; k++) {
        int i = tid + k * 256;
        int ea = eass[i];
#pragma unroll
        for (int e = 0; e < E_; e++) fc[e] += (ea == e) ? 1.f : 0.f;
    }
#pragma unroll
    for (int e = 0; e < E_; e++) { red[tid][e] = ps[e]; red[tid][8 + e] = fc[e]; }
    if (tid < E_) lcnt[tid] = 0;
    __syncthreads();
    for (int s = 128; s > 0; s >>= 1) {
        if (tid < s)
#pragma unroll
            for (int j = 0; j < 16; j++) red[tid][j] += red[tid + s][j];
        __syncthreads();
    }
    if (tid == 0) {
        float s = 0.f;
        for (int e = 0; e < E_; e++)
            s += (red[0][e] * (1.f / 1024.f)) * (red[0][8 + e] * (1.f / 1024.f));
        aux_out[0] = (float)E_ * s;
    }
    for (int k = 0; k < 8; k++) {
        int i = tid + k * 256;
        int ea = eass[i];
        int pos = atomicAdd(&lcnt[ea], 1);
        buckets[ea * NPAIR + pos] = i;
    }
    __syncthreads();
    if (tid < E_) bucket_cnt[tid] = lcnt[tid];
}

// ---------------- pack fp32 [k][n] -> bf16 B-tiles (LDS image, swizzle baked) --------
// u16 index: (nt*32+ks)*4096 + n_loc*32 + p*8 + j
// content:   W[(ks*32 + g*8 + j)*1024 + nt*128 + n_loc],  g=(p-((n_loc>>1)&3))&3
__global__ __launch_bounds__(256) void pack_b(
    const float* __restrict__ src, u16* __restrict__ dst)
{
    __shared__ float t[64][65];          // t[k_rel][n_rel]
    src += (size_t)blockIdx.z << 20;
    dst += (size_t)blockIdx.z << 20;
    int k0 = blockIdx.y * 64, n0 = blockIdx.x * 64;
    int tid = threadIdx.x;
#pragma unroll
    for (int p = 0; p < 4; p++) {
        int e4 = tid + 256 * p;          // 1024 float4 = 64 k-rows x 16 float4
        int r = e4 >> 4, c4 = e4 & 15;
        float4 v = *(const float4*)&src[(size_t)(k0 + r) * 1024 + n0 + c4 * 4];
        t[r][c4 * 4 + 0] = v.x; t[r][c4 * 4 + 1] = v.y;
        t[r][c4 * 4 + 2] = v.z; t[r][c4 * 4 + 3] = v.w;
    }
    __syncthreads();
    int c = tid & 63, ks_rel = (tid >> 6) & 1, ph = tid >> 7;
    int n_glob = n0 + c, nt = n_glob >> 7, n_loc = n_glob & 127;
    int ks = (k0 >> 5) + ks_rel;
    u16* ob = dst + (((size_t)(nt * 32 + ks)) << 12) + n_loc * 32;
#pragma unroll
    for (int pp = 0; pp < 2; pp++) {
        int p = ph * 2 + pp;
        int g = (p - ((n_loc >> 1) & 3)) & 3;
        int kb = ks_rel * 32 + g * 8;
        ushort4 o1, o2;
        o1.x = f2bf(t[kb + 0][c]); o1.y = f2bf(t[kb + 1][c]);
        o1.z = f2bf(t[kb + 2][c]); o1.w = f2bf(t[kb + 3][c]);
        o2.x = f2bf(t[kb + 4][c]); o2.y = f2bf(t[kb + 5][c]);
        o2.z = f2bf(t[kb + 6][c]); o2.w = f2bf(t[kb + 7][c]);
        *(ushort4*)&ob[p * 8]     = o1;
        *(ushort4*)&ob[p * 8 + 4] = o2;
    }
}

// ---------------- pipelined 128x128x32 MFMA mainloop (4-stage, depth-3) ----------------
// B is pre-packed sequential (8 KB per step); A is row-major staged with swizzle.
__device__ __forceinline__ void mfma_mainloop128(
    const u16* __restrict__ gA0, const u16* __restrict__ gA1,
    const u16* __restrict__ gB0, const u16* __restrict__ gB1,
    u16* AsBase, u16* BsBase, int w,
    const int offA[4], const int offB[4], f32x4 acc[4][4])
{
#define ISSUE(s) { int buf_ = (s) & 3;                                         \
    gload_lds16(gA0 + (s) * 32,   AsBase + buf_ * 4096 + w * 512);             \
    gload_lds16(gA1 + (s) * 32,   AsBase + buf_ * 4096 + 2048 + w * 512);      \
    gload_lds16(gB0 + (s) * 4096, BsBase + buf_ * 4096 + w * 512);             \
    gload_lds16(gB1 + (s) * 4096, BsBase + buf_ * 4096 + 2048 + w * 512); }
    ISSUE(0); ISSUE(1); ISSUE(2);
    for (int k = 0; k < 32; k++) {
        if (k < 30)       asm volatile("s_waitcnt vmcnt(8)" ::: "memory");
        else if (k == 30) asm volatile("s_waitcnt vmcnt(4)" ::: "memory");
        else              asm volatile("s_waitcnt vmcnt(0)" ::: "memory");
        __builtin_amdgcn_s_barrier();   // stage-k data in LDS for all waves
        asm volatile("" ::: "memory");
        if (k < 29) ISSUE(k + 3);       // overwrites buffer (k-1)&3 — retired per barrier
        const u16* As = AsBase + (k & 3) * 4096;
        const u16* Bs = BsBase + (k & 3) * 4096;
        bf16x8 af[4], bfr[4];
#pragma unroll
        for (int i = 0; i < 4; i++) af[i] = *(const bf16x8*)&As[offA[i]];
#pragma unroll
        for (int j = 0; j < 4; j++) bfr[j] = *(const bf16x8*)&Bs[offB[j]];
#pragma unroll
        for (int i = 0; i < 4; i++)
#pragma unroll
            for (int j = 0; j < 4; j++)
                acc[i][j] = __builtin_amdgcn_mfma_f32_16x16x32_bf16(
                    af[i], bfr[j], acc[i][j], 0, 0, 0);
        asm volatile("" ::: "memory");
    }
#undef ISSUE
}

__device__ __forceinline__ void frag_offsets(int base, int lm, int g, int off[4])
{
#pragma unroll
    for (int i = 0; i < 4; i++) {
        int m = base + i * 16 + lm;
        off[i] = m * 32 + (((g + ((m >> 1) & 3)) & 3) << 3);
    }
}

// ---------------- fused KV (dense) + q (routed) GEMM, 128x128, pipelined ----------------
// bx < 128: KV  (mt=bx&7, nt=bx>>3, N=2048)  -> Kb/Vb attention layout (+bias)
// bx >= 128: q  (b2: e=(b2>>4)&7, mt=b2&15, nt=b2>>7) -> Qb layout
__global__ __launch_bounds__(256, 2) void gemm_fused(
    const u16* __restrict__ xb, const u16* __restrict__ Wkv_p,
    const float* __restrict__ bkv, const u16* __restrict__ Win_p,
    const int* __restrict__ bucket_cnt, const int* __restrict__ buckets,
    u16* __restrict__ Kb, u16* __restrict__ Vb, u16* __restrict__ Qb)
{
    __shared__ __align__(16) u16 As[4 * 4096];
    __shared__ __align__(16) u16 Bs[4 * 4096];
    __shared__ int rowArr[128];
    int bx = blockIdx.x;
    int tid = threadIdx.x;
    bool isKV = bx < 128;
    int e, mt, nt, cnt, rowshift;
    const u16* Wp;
    if (isKV) {
        mt = bx & 7; nt = bx >> 3; cnt = NTOK; rowshift = 0; Wp = Wkv_p; e = 0;
    } else {
        int b2 = bx - 128;
        e = (b2 >> 4) & 7; mt = b2 & 15; nt = b2 >> 7;
        cnt = bucket_cnt[e]; rowshift = 1;
        Wp = Win_p + ((size_t)e << 20);
    }
    int m0 = mt * 128;
    if (m0 >= cnt) return;
    int cl = min(cnt - m0, 128);
    if (tid < 128) {
        int idx = m0 + tid;
        rowArr[tid] = isKV ? idx : buckets[e * NPAIR + (idx < cnt ? idx : cnt - 1)];
    }
    __syncthreads();

    int r0 = tid >> 2, p0 = tid & 3;
    int g0 = (p0 - ((r0 >> 1) & 3)) & 3;
    const u16* gA0 = xb + (size_t)(rowArr[r0] >> rowshift) * 1024 + g0 * 8;
    const u16* gA1 = xb + (size_t)(rowArr[r0 + 64] >> rowshift) * 1024 + g0 * 8;
    const u16* gB0 = Wp + (((size_t)(nt * 32)) << 12) + tid * 8;   // packed: tid*16B
    const u16* gB1 = gB0 + 2048;

    int w = tid >> 6, lane = tid & 63, lm = lane & 15, g = lane >> 4;
    int mq = w >> 1, nq = w & 1;
    int offA[4], offB[4];
    frag_offsets(mq * 64, lm, g, offA);
    frag_offsets(nq * 64, lm, g, offB);
    f32x4 acc[4][4];
#pragma unroll
    for (int i = 0; i < 4; i++)
#pragma unroll
        for (int j = 0; j < 4; j++) acc[i][j] = 0;

    mfma_mainloop128(gA0, gA1, gB0, gB1, As, Bs, w, offA, offB, acc);

#pragma unroll
    for (int i = 0; i < 4; i++) {
#pragma unroll
        for (int reg = 0; reg < 4; reg++) {
            int lrow = mq * 64 + i * 16 + g * 4 + reg;
            if (lrow < cl) {
                int orow = rowArr[lrow];
#pragma unroll
                for (int j = 0; j < 4; j++) {
                    int col = nt * 128 + nq * 64 + j * 16 + lm;
                    float v = acc[i][j][reg];
                    if (isKV) {
                        v += bkv[col];
                        int tb = orow >> 9, tj = orow & 511;
                        int cc = col & 1023;
                        int hh = cc >> 7, dd = cc & 127;
                        u16* dst = (col < 1024) ? Kb : Vb;
                        dst[(((size_t)(tb * 8 + hh) * 512 + tj) << 7) + dd] = f2bf(v);
                    } else {
                        int pb = orow >> 10, pi = (orow >> 1) & 511, ps = orow & 1;
                        int hh = col >> 7, dd = col & 127;
                        Qb[((((size_t)(pb * 16 + ps * 8 + hh)) * 512 + pi) << 7) + dd] = f2bf(v);
                    }
                }
            }
        }
    }
}

// ---------------- W_out routed GEMM, 128x128, pipelined, fp32 out ----------------
// grid 1024: e=(bx>>4)&7, mt=bx&15, nt=bx>>7
__global__ __launch_bounds__(256, 2) void gemm_wout(
    const u16* __restrict__ yb, const u16* __restrict__ Wout_p,
    const int* __restrict__ bucket_cnt, const int* __restrict__ buckets,
    float* __restrict__ Out)
{
    __shared__ __align__(16) u16 As[4 * 4096];
    __shared__ __align__(16) u16 Bs[4 * 4096];
    __shared__ int rowArr[128];
    int bx = blockIdx.x;
    int tid = threadIdx.x;
    int e = (bx >> 4) & 7, mt = bx & 15, nt = bx >> 7;
    int cnt = bucket_cnt[e];
    int m0 = mt * 128;
    if (m0 >= cnt) return;
    int cl = min(cnt - m0, 128);
    if (tid < 128) {
        int idx = m0 + tid;
        rowArr[tid] = buckets[e * NPAIR + (idx < cnt ? idx : cnt - 1)];
    }
    __syncthreads();

    int r0 = tid >> 2, p0 = tid & 3;
    int g0 = (p0 - ((r0 >> 1) & 3)) & 3;
    const u16* gA0 = yb + (size_t)rowArr[r0] * 1024 + g0 * 8;
    const u16* gA1 = yb + (size_t)rowArr[r0 + 64] * 1024 + g0 * 8;
    const u16* gB0 = Wout_p + ((size_t)e << 20) + (((size_t)(nt * 32)) << 12) + tid * 8;
    const u16* gB1 = gB0 + 2048;

    int w = tid >> 6, lane = tid & 63, lm = lane & 15, g = lane >> 4;
    int mq = w >> 1, nq = w & 1;
    int offA[4], offB[4];
    frag_offsets(mq * 64, lm, g, offA);
    frag_offsets(nq * 64, lm, g, offB);
    f32x4 acc[4][4];
#pragma unroll
    for (int i = 0; i < 4; i++)
#pragma unroll
        for (int j = 0; j < 4; j++) acc[i][j] = 0;

    mfma_mainloop128(gA0, gA1, gB0, gB1, As, Bs, w, offA, offB, acc);

#pragma unroll
    for (int i = 0; i < 4; i++) {
#pragma unroll
        for (int reg = 0; reg < 4; reg++) {
            int lrow = mq * 64 + i * 16 + g * 4 + reg;
            if (lrow < cl) {
                int orow = rowArr[lrow];
#pragma unroll
                for (int j = 0; j < 4; j++) {
                    int col = nt * 128 + nq * 64 + j * 16 + lm;
                    Out[(size_t)orow * 1024 + col] = acc[i][j][reg];
                }
            }
        }
    }
}

// ---------------- Vb [bh][j][d] -> Vtb [bh][d][j] (bf16 transpose) ----------------
__global__ __launch_bounds__(256) void vtrans(
    const u16* __restrict__ Vb, u16* __restrict__ Vtb)
{
    __shared__ u16 t[64][72];
    int bh = blockIdx.x;
    int d0 = blockIdx.y * 64;
    int j0 = blockIdx.z * 64;
    int tid = threadIdx.x;
#pragma unroll
    for (int p = 0; p < 2; p++) {
        int c = tid + 256 * p;
        int jr = c >> 3, c8 = c & 7;
        *(bf16x8*)&t[jr][c8 * 8] =
            *(const bf16x8*)&Vb[((size_t)bh * 512 + j0 + jr) * 128 + d0 + c8 * 8];
    }
    __syncthreads();
#pragma unroll
    for (int p = 0; p < 2; p++) {
        int c = tid + 256 * p;
        int dr = c >> 3, j8 = c & 7;
        bf16x8 o;
#pragma unroll
        for (int k = 0; k < 8; k++) o[k] = (short)t[j8 * 8 + k][dr];
        *(bf16x8*)&Vtb[((size_t)bh * 128 + d0 + dr) * 512 + j0 + j8 * 8] = o;
    }
}

// ---------------- stick-breaking flash attention, MFMA ----------------
__global__ __launch_bounds__(256) void attn_kernel(
    const u16* __restrict__ Qb, const u16* __restrict__ Kb,
    const u16* __restrict__ Vtb, const float* __restrict__ gates,
    u16* __restrict__ yb)
{
    __shared__ __align__(16) u16 Qs[32 * 136];
    __shared__ __align__(16) u16 Ks[32 * 136];
    __shared__ __align__(16) u16 Vts[128 * 40];
    __shared__ __align__(16) float sw[32 * 36];
    __shared__ __align__(16) u16 wt[32 * 40];

    int combo = blockIdx.x;
    int b = combo >> 4, slot = (combo >> 3) & 1, h = combo & 7;
    int bh = b * 8 + h;
    const u16* Qbase = Qb  + ((size_t)combo << 16);
    const u16* Kbase = Kb  + ((size_t)bh << 16);
    const u16* Vbase = Vtb + ((size_t)bh << 16);

    int tid = threadIdx.x;
    int w = tid >> 6, lane = tid & 63, lm = lane & 15, g = lane >> 4;
    int mh = w >> 1, nh = w & 1, dsel = w & 1;
    int srow = tid >> 3, st = tid & 7;
    int rowlane = lane & 56;
    const float SCALE = 0.08838834764831845f;

    for (int seg = 0; seg < 2; seg++) {
        int it = seg ? (15 - blockIdx.y) : blockIdx.y;
        int i0 = it * 32;
        __syncthreads();
#pragma unroll
        for (int p = 0; p < 2; p++) {
            int c = tid + 256 * p;
            int r = c >> 4, c8 = c & 15;
            *(bf16x8*)&Qs[r * 136 + c8 * 8] =
                *(const bf16x8*)&Qbase[(size_t)(i0 + r) * 128 + c8 * 8];
        }
        f32x4 pacc[4];
#pragma unroll
        for (int q = 0; q < 4; q++) pacc[q] = 0;
        float running = 0.f;

        for (int jt = it; jt >= 0; jt--) {
            int j0 = jt * 32;
            __syncthreads();
#pragma unroll
            for (int p = 0; p < 2; p++) {
                int c = tid + 256 * p;
                int r = c >> 4, c8 = c & 15;
                *(bf16x8*)&Ks[r * 136 + c8 * 8] =
                    *(const bf16x8*)&Kbase[(size_t)(j0 + r) * 128 + c8 * 8];
            }
#pragma unroll
            for (int p = 0; p < 2; p++) {
                int c = tid + 256 * p;
                int d = c >> 2, j8 = c & 3;
                *(bf16x8*)&Vts[d * 40 + j8 * 8] =
                    *(const bf16x8*)&Vbase[(size_t)d * 512 + j0 + j8 * 8];
            }
            __syncthreads();
            f32x4 sacc = 0;
#pragma unroll
            for (int ks = 0; ks < 4; ks++) {
                bf16x8 aq = *(const bf16x8*)&Qs[(mh * 16 + lm) * 136 + ks * 32 + g * 8];
                bf16x8 bk = *(const bf16x8*)&Ks[(nh * 16 + lm) * 136 + ks * 32 + g * 8];
                sacc = __builtin_amdgcn_mfma_f32_16x16x32_bf16(aq, bk, sacc, 0, 0, 0);
            }
#pragma unroll
            for (int reg = 0; reg < 4; reg++)
                sw[(mh * 16 + g * 4 + reg) * 36 + nh * 16 + lm] = sacc[reg] * SCALE;
            __syncthreads();
            {
                float4 sv = *(const float4*)&sw[srow * 36 + st * 4];
                float sarr[4] = {sv.x, sv.y, sv.z, sv.w};
                int ig = i0 + srow;
                float lsig[4], lb[4];
#pragma unroll
                for (int c2 = 0; c2 < 4; c2++) {
                    int jg = j0 + st * 4 + c2;
                    float sc = sarr[c2];
                    float a  = fabsf(sc);
                    float tl = log1pf(__expf(-a));
                    lsig[c2] = (sc >= 0.f) ? -tl : sc - tl;
                    lb[c2]   = (jg <= ig) ? -(tl + fmaxf(sc, 0.f)) : 0.f;
                }
                float suf[4];
                suf[3] = 0.f;
                suf[2] = lb[3];
                suf[1] = lb[2] + lb[3];
                suf[0] = lb[1] + suf[1];
                float total = lb[0] + suf[0];
                float incl = total;
                float y1 = __shfl_down(incl, 1, 64); if (st < 7) incl += y1;
                float y2 = __shfl_down(incl, 2, 64); if (st < 6) incl += y2;
                float y4 = __shfl_down(incl, 4, 64); if (st < 4) incl += y4;
                float basev = (incl - total) + running;
                ushort4 wo;
                float wv;
                int jgc = j0 + st * 4;
                wv = (jgc + 0 <= ig) ? __expf(lsig[0] + suf[0] + basev) : 0.f; wo.x = f2bf(wv);
                wv = (jgc + 1 <= ig) ? __expf(lsig[1] + suf[1] + basev) : 0.f; wo.y = f2bf(wv);
                wv = (jgc + 2 <= ig) ? __expf(lsig[2] + suf[2] + basev) : 0.f; wo.z = f2bf(wv);
                wv = (jgc + 3 <= ig) ? __expf(lsig[3] + suf[3] + basev) : 0.f; wo.w = f2bf(wv);
                running += __shfl(incl, rowlane, 64);
                *(ushort4*)&wt[srow * 40 + st * 4] = wo;
            }
            __syncthreads();
            bf16x8 aw = *(const bf16x8*)&wt[(mh * 16 + lm) * 40 + g * 8];
#pragma unroll
            for (int q = 0; q < 4; q++) {
                int dt = q * 2 + dsel;
                bf16x8 bv8 = *(const bf16x8*)&Vts[(dt * 16 + lm) * 40 + g * 8];
                pacc[q] = __builtin_amdgcn_mfma_f32_16x16x32_bf16(aw, bv8, pacc[q], 0, 0, 0);
            }
        }
#pragma unroll
        for (int reg = 0; reg < 4; reg++) {
            int i = i0 + mh * 16 + g * 4 + reg;
            size_t pair = ((size_t)(b * 512 + i)) * 2 + slot;
            float gt = gates[pair];
#pragma unroll
            for (int q = 0; q < 4; q++) {
                int d = (q * 2 + dsel) * 16 + lm;
                yb[pair * 1024 + h * 128 + d] = f2bf(pacc[q][reg] * gt);
            }
        }
    }
}

// ---------------- combine pairs ----------------
__global__ __launch_bounds__(256) void combine_kernel(
    const float* __restrict__ tmp, float* __restrict__ out)
{
    int idx = blockIdx.x * 256 + threadIdx.x;
    int token = idx >> 8;
    int c4 = idx & 255;
    const float4* t4 = (const float4*)tmp;
    float4 a = t4[(size_t)(token * 2) * 256 + c4];
    float4 b = t4[(size_t)(token * 2 + 1) * 256 + c4];
    float4 r;
    r.x = a.x + b.x; r.y = a.y + b.y; r.z = a.z + b.z; r.w = a.w + b.w;
    ((float4*)out)[idx] = r;
}

extern "C" void kernel_launch(void* const* d_in, const int* in_sizes, int n_in,
                              void* d_out, int out_size, void* d_ws, size_t ws_size,
                              hipStream_t stream)
{
    const float* x     = (const float*)d_in[0];
    const float* Wg    = (const float*)d_in[1];
    const float* W_in  = (const float*)d_in[2];
    const float* W_out = (const float*)d_in[3];
    const float* Wk    = (const float*)d_in[4];
    const float* bk    = (const float*)d_in[5];
    const float* Wv    = (const float*)d_in[6];
    const float* bv    = (const float*)d_in[7];

    char* ws = (char*)d_ws;
    int*   bucket_cnt = (int*)ws;
    size_t off = 256;
    float* gates = (float*)(ws + off); off += (size_t)NPAIR * 4;
    int* buckets = (int*)(ws + off);   off += (size_t)E_ * NPAIR * 4;
    float* bkv   = (float*)(ws + off); off += 2048 * 4;
    float* probs = (float*)(ws + off); off += (size_t)NTOK * E_ * 4;
    int*   eass  = (int*)(ws + off);   off += (size_t)NPAIR * 4;
    off = (off + 255) & ~(size_t)255;
    u16* xb    = (u16*)(ws + off); off += (size_t)NTOK * C_ * 2;
    u16* Wkv_p = (u16*)(ws + off); off += (size_t)2048 * 1024 * 2;
    u16* wp    = (u16*)(ws + off); off += (size_t)E_ * 1024 * 1024 * 2;   // W_in_p then W_out_p
    u16* yb    = (u16*)(ws + off); off += (size_t)NPAIR * AH_ * 2;
    u16* Qbuf  = (u16*)(ws + off); off += (size_t)32 * 512 * 128 * 2;
    u16* Kbuf  = (u16*)(ws + off); off += (size_t)16 * 512 * 128 * 2;
    u16* Vbuf  = (u16*)(ws + off); off += (size_t)16 * 512 * 128 * 2;
    u16* Vtbuf = (u16*)(ws + off); off += (size_t)16 * 128 * 512 * 2;
    float* tmp = (float*)(ws + off); off += (size_t)NPAIR * AH_ * 4;

    gate_kernel<<<NTOK, 64, 0, stream>>>(x, Wg, xb, gates, probs, eass);
    route_kernel<<<1, 256, 0, stream>>>(probs, eass, bk, bv, bucket_cnt,
                                        buckets, bkv,
                                        (float*)d_out + (out_size - 1));
    pack_b<<<dim3(16, 16, 8), 256, 0, stream>>>(W_in, wp);
    pack_b<<<dim3(16, 16, 1), 256, 0, stream>>>(Wk, Wkv_p);
    pack_b<<<dim3(16, 16, 1), 256, 0, stream>>>(Wv, Wkv_p + ((size_t)1 << 20));

    // fused KV (dense, 128 blocks) + q (routed, 1024 logical blocks)
    gemm_fused<<<128 + 1024, 256, 0, stream>>>(xb, Wkv_p, bkv, wp, bucket_cnt,
                                               buckets, Kbuf, Vbuf, Qbuf);
    vtrans<<<dim3(16, 2, 8), 256, 0, stream>>>(Vbuf, Vtbuf);

    attn_kernel<<<dim3(32, 8), 256, 0, stream>>>(Qbuf, Kbuf, Vtbuf, gates, yb);

    pack_b<<<dim3(16, 16, 8), 256, 0, stream>>>(W_out, wp);   // wp reused after q-gemm
    gemm_wout<<<1024, 256, 0, stream>>>(yb, wp, bucket_cnt, buckets, tmp);

    combine_kernel<<<(NTOK * C_ / 4) / 256, 256, 0, stream>>>(tmp, (float*)d_out);
}

// Round 8
// 299.559 us; speedup vs baseline: 1.0836x; 1.0836x over previous
//
#include <hip/hip_runtime.h>
#include <cmath>

#define B_    2
#define T_    512
#define C_    1024
#define E_    8
#define NTOK  1024
#define NPAIR 2048
#define AH_   1024
#define NH_   8
#define HS_   128

typedef unsigned short u16;
typedef __attribute__((ext_vector_type(8))) short bf16x8;
typedef __attribute__((ext_vector_type(4))) float f32x4;

__device__ __forceinline__ u16 f2bf(float f) {
    union { float f; unsigned u; } v; v.f = f;
    unsigned r = v.u + 0x7fff + ((v.u >> 16) & 1);   // RNE
    return (u16)(r >> 16);
}

__device__ __forceinline__ void gload_lds16(const void* g, void* l) {
    __builtin_amdgcn_global_load_lds(
        (const __attribute__((address_space(1))) void*)g,
        (__attribute__((address_space(3))) void*)l, 16, 0, 0);
}

// ---------------- kernel 1: gate logits, top-2, x->bf16 (NO global atomics) ----------------
__global__ __launch_bounds__(64) void gate_kernel(
    const float* __restrict__ x, const float* __restrict__ Wg,
    u16* __restrict__ xb, float* __restrict__ gates,
    float* __restrict__ probs, int* __restrict__ eass)
{
    int token = blockIdx.x;
    int lane  = threadIdx.x;
    const float* xr = x + (size_t)token * C_;
    u16* xbr = xb + (size_t)token * C_;
    float acc[E_];
#pragma unroll
    for (int e = 0; e < E_; e++) acc[e] = 0.f;
    for (int c = lane; c < C_; c += 64) {
        float xv = xr[c];
        xbr[c] = f2bf(xv);
        const float* wr = Wg + c * E_;
#pragma unroll
        for (int e = 0; e < E_; e++) acc[e] += xv * wr[e];
    }
#pragma unroll
    for (int e = 0; e < E_; e++) {
        float v = acc[e];
        v += __shfl_xor(v, 32); v += __shfl_xor(v, 16); v += __shfl_xor(v, 8);
        v += __shfl_xor(v, 4);  v += __shfl_xor(v, 2);  v += __shfl_xor(v, 1);
        acc[e] = v;
    }
    if (lane == 0) {
        int i0 = 0; float v0 = acc[0];
        for (int e = 1; e < E_; e++) if (acc[e] > v0) { v0 = acc[e]; i0 = e; }
        int i1 = -1; float v1 = -3.4e38f;
        for (int e = 0; e < E_; e++) if (e != i0 && acc[e] > v1) { v1 = acc[e]; i1 = e; }
        float e1  = __expf(v1 - v0);
        float inv = 1.f / (1.f + e1);
        gates[token * 2 + 0] = inv;
        gates[token * 2 + 1] = e1 * inv;
        float s = 0.f; float pe[E_];
        for (int e = 0; e < E_; e++) { pe[e] = __expf(acc[e] - v0); s += pe[e]; }
        float sinv = 1.f / s;
        for (int e = 0; e < E_; e++) probs[token * E_ + e] = pe[e] * sinv;
        eass[token * 2 + 0] = i0;
        eass[token * 2 + 1] = i1;
    }
}

// ---------------- kernel 1b: aux-loss reduce + bucket build (single block) ----------------
__global__ __launch_bounds__(256) void route_kernel(
    const float* __restrict__ probs, const int* __restrict__ eass,
    const float* __restrict__ bk, const float* __restrict__ bv,
    int* __restrict__ bucket_cnt, int* __restrict__ buckets,
    float* __restrict__ bkv, float* __restrict__ aux_out)
{
    __shared__ float red[256][17];
    __shared__ int lcnt[E_];
    int tid = threadIdx.x;
    for (int i = tid; i < 1024; i += 256) {
        bkv[i] = bk[i];
        bkv[i + 1024] = bv[i];
    }
    float ps[E_], fc[E_];
#pragma unroll
    for (int e = 0; e < E_; e++) { ps[e] = 0.f; fc[e] = 0.f; }
    for (int k = 0; k < 4; k++) {
        int row = tid + k * 256;
#pragma unroll
        for (int e = 0; e < E_; e++) ps[e] += probs[row * E_ + e];
    }
    for (int k = 0; k < 8; k++) {
        int i = tid + k * 256;
        int ea = eass[i];
#pragma unroll
        for (int e = 0; e < E_; e++) fc[e] += (ea == e) ? 1.f : 0.f;
    }
#pragma unroll
    for (int e = 0; e < E_; e++) { red[tid][e] = ps[e]; red[tid][8 + e] = fc[e]; }
    if (tid < E_) lcnt[tid] = 0;
    __syncthreads();
    for (int s = 128; s > 0; s >>= 1) {
        if (tid < s)
#pragma unroll
            for (int j = 0; j < 16; j++) red[tid][j] += red[tid + s][j];
        __syncthreads();
    }
    if (tid == 0) {
        float s = 0.f;
        for (int e = 0; e < E_; e++)
            s += (red[0][e] * (1.f / 1024.f)) * (red[0][8 + e] * (1.f / 1024.f));
        aux_out[0] = (float)E_ * s;
    }
    for (int k = 0; k < 8; k++) {
        int i = tid + k * 256;
        int ea = eass[i];
        int pos = atomicAdd(&lcnt[ea], 1);
        buckets[ea * NPAIR + pos] = i;
    }
    __syncthreads();
    if (tid < E_) bucket_cnt[tid] = lcnt[tid];
}

// ---------------- pack fp32 [k][n] -> bf16 B-tiles (LDS image, swizzle baked) --------
// u16 index: (nt*32+ks)*4096 + n_loc*32 + p*8 + j
// content:   W[(ks*32 + g*8 + j)*1024 + nt*128 + n_loc],  g=(p-((n_loc>>1)&3))&3
__global__ __launch_bounds__(256) void pack_b(
    const float* __restrict__ src, u16* __restrict__ dst)
{
    __shared__ float t[64][65];          // t[k_rel][n_rel]
    src += (size_t)blockIdx.z << 20;
    dst += (size_t)blockIdx.z << 20;
    int k0 = blockIdx.y * 64, n0 = blockIdx.x * 64;
    int tid = threadIdx.x;
#pragma unroll
    for (int p = 0; p < 4; p++) {
        int e4 = tid + 256 * p;          // 1024 float4 = 64 k-rows x 16 float4
        int r = e4 >> 4, c4 = e4 & 15;
        float4 v = *(const float4*)&src[(size_t)(k0 + r) * 1024 + n0 + c4 * 4];
        t[r][c4 * 4 + 0] = v.x; t[r][c4 * 4 + 1] = v.y;
        t[r][c4 * 4 + 2] = v.z; t[r][c4 * 4 + 3] = v.w;
    }
    __syncthreads();
    int c = tid & 63, ks_rel = (tid >> 6) & 1, ph = tid >> 7;
    int n_glob = n0 + c, nt = n_glob >> 7, n_loc = n_glob & 127;
    int ks = (k0 >> 5) + ks_rel;
    u16* ob = dst + (((size_t)(nt * 32 + ks)) << 12) + n_loc * 32;
#pragma unroll
    for (int pp = 0; pp < 2; pp++) {
        int p = ph * 2 + pp;
        int g = (p - ((n_loc >> 1) & 3)) & 3;
        int kb = ks_rel * 32 + g * 8;
        ushort4 o1, o2;
        o1.x = f2bf(t[kb + 0][c]); o1.y = f2bf(t[kb + 1][c]);
        o1.z = f2bf(t[kb + 2][c]); o1.w = f2bf(t[kb + 3][c]);
        o2.x = f2bf(t[kb + 4][c]); o2.y = f2bf(t[kb + 5][c]);
        o2.z = f2bf(t[kb + 6][c]); o2.w = f2bf(t[kb + 7][c]);
        *(ushort4*)&ob[p * 8]     = o1;
        *(ushort4*)&ob[p * 8 + 4] = o2;
    }
}

// ---------------- m97-style 128x128x32 MFMA mainloop (single buffer, wait-all) ------
// LDS per block: As 8 KB + Bs 8 KB. High occupancy does the latency hiding (m114).
__device__ __forceinline__ void mfma_mainloop128(
    const u16* __restrict__ gA0, const u16* __restrict__ gA1,
    const u16* __restrict__ gB0, const u16* __restrict__ gB1,
    u16* As, u16* Bs, int w,
    const int offA[4], const int offB[4], f32x4 acc[4][4])
{
    for (int k = 0; k < 32; k++) {
        __syncthreads();
        gload_lds16(gA0 + k * 32,   As + w * 512);
        gload_lds16(gA1 + k * 32,   As + 2048 + w * 512);
        gload_lds16(gB0 + k * 4096, Bs + w * 512);
        gload_lds16(gB1 + k * 4096, Bs + 2048 + w * 512);
        asm volatile("s_waitcnt vmcnt(0)" ::: "memory");
        __syncthreads();
        bf16x8 af[4], bfr[4];
#pragma unroll
        for (int i = 0; i < 4; i++) af[i] = *(const bf16x8*)&As[offA[i]];
#pragma unroll
        for (int j = 0; j < 4; j++) bfr[j] = *(const bf16x8*)&Bs[offB[j]];
#pragma unroll
        for (int i = 0; i < 4; i++)
#pragma unroll
            for (int j = 0; j < 4; j++)
                acc[i][j] = __builtin_amdgcn_mfma_f32_16x16x32_bf16(
                    af[i], bfr[j], acc[i][j], 0, 0, 0);
    }
}

__device__ __forceinline__ void frag_offsets(int base, int lm, int g, int off[4])
{
#pragma unroll
    for (int i = 0; i < 4; i++) {
        int m = base + i * 16 + lm;
        off[i] = m * 32 + (((g + ((m >> 1) & 3)) & 3) << 3);
    }
}

// ---------------- fused KV (dense) + q (routed) GEMM, 128x128 ----------------
// bx < 128: KV  (mt=bx&7, nt=bx>>3, N=2048)  -> Kb/Vb attention layout (+bias)
// bx >= 128: q  (b2: e=(b2>>4)&7, mt=b2&15, nt=b2>>7) -> Qb layout
__global__ __launch_bounds__(256) void gemm_fused(
    const u16* __restrict__ xb, const u16* __restrict__ Wkv_p,
    const float* __restrict__ bkv, const u16* __restrict__ Win_p,
    const int* __restrict__ bucket_cnt, const int* __restrict__ buckets,
    u16* __restrict__ Kb, u16* __restrict__ Vb, u16* __restrict__ Qb)
{
    __shared__ __align__(16) u16 As[4096];
    __shared__ __align__(16) u16 Bs[4096];
    __shared__ int rowArr[128];
    int bx = blockIdx.x;
    int tid = threadIdx.x;
    bool isKV = bx < 128;
    int e, mt, nt, cnt, rowshift;
    const u16* Wp;
    if (isKV) {
        mt = bx & 7; nt = bx >> 3; cnt = NTOK; rowshift = 0; Wp = Wkv_p; e = 0;
    } else {
        int b2 = bx - 128;
        e = (b2 >> 4) & 7; mt = b2 & 15; nt = b2 >> 7;
        cnt = bucket_cnt[e]; rowshift = 1;
        Wp = Win_p + ((size_t)e << 20);
    }
    int m0 = mt * 128;
    if (m0 >= cnt) return;
    int cl = min(cnt - m0, 128);
    if (tid < 128) {
        int idx = m0 + tid;
        rowArr[tid] = isKV ? idx : buckets[e * NPAIR + (idx < cnt ? idx : cnt - 1)];
    }
    __syncthreads();

    int r0 = tid >> 2, p0 = tid & 3;
    int g0 = (p0 - ((r0 >> 1) & 3)) & 3;
    const u16* gA0 = xb + (size_t)(rowArr[r0] >> rowshift) * 1024 + g0 * 8;
    const u16* gA1 = xb + (size_t)(rowArr[r0 + 64] >> rowshift) * 1024 + g0 * 8;
    const u16* gB0 = Wp + (((size_t)(nt * 32)) << 12) + tid * 8;   // packed: tid*16B
    const u16* gB1 = gB0 + 2048;

    int w = tid >> 6, lane = tid & 63, lm = lane & 15, g = lane >> 4;
    int mq = w >> 1, nq = w & 1;
    int offA[4], offB[4];
    frag_offsets(mq * 64, lm, g, offA);
    frag_offsets(nq * 64, lm, g, offB);
    f32x4 acc[4][4];
#pragma unroll
    for (int i = 0; i < 4; i++)
#pragma unroll
        for (int j = 0; j < 4; j++) acc[i][j] = 0;

    mfma_mainloop128(gA0, gA1, gB0, gB1, As, Bs, w, offA, offB, acc);

#pragma unroll
    for (int i = 0; i < 4; i++) {
#pragma unroll
        for (int reg = 0; reg < 4; reg++) {
            int lrow = mq * 64 + i * 16 + g * 4 + reg;
            if (lrow < cl) {
                int orow = rowArr[lrow];
#pragma unroll
                for (int j = 0; j < 4; j++) {
                    int col = nt * 128 + nq * 64 + j * 16 + lm;
                    float v = acc[i][j][reg];
                    if (isKV) {
                        v += bkv[col];
                        int tb = orow >> 9, tj = orow & 511;
                        int cc = col & 1023;
                        int hh = cc >> 7, dd = cc & 127;
                        u16* dst = (col < 1024) ? Kb : Vb;
                        dst[(((size_t)(tb * 8 + hh) * 512 + tj) << 7) + dd] = f2bf(v);
                    } else {
                        int pb = orow >> 10, pi = (orow >> 1) & 511, ps = orow & 1;
                        int hh = col >> 7, dd = col & 127;
                        Qb[((((size_t)(pb * 16 + ps * 8 + hh)) * 512 + pi) << 7) + dd] = f2bf(v);
                    }
                }
            }
        }
    }
}

// ---------------- W_out routed GEMM, 128x128, fp32 out ----------------
// grid 1024: e=(bx>>4)&7, mt=bx&15, nt=bx>>7
__global__ __launch_bounds__(256) void gemm_wout(
    const u16* __restrict__ yb, const u16* __restrict__ Wout_p,
    const int* __restrict__ bucket_cnt, const int* __restrict__ buckets,
    float* __restrict__ Out)
{
    __shared__ __align__(16) u16 As[4096];
    __shared__ __align__(16) u16 Bs[4096];
    __shared__ int rowArr[128];
    int bx = blockIdx.x;
    int tid = threadIdx.x;
    int e = (bx >> 4) & 7, mt = bx & 15, nt = bx >> 7;
    int cnt = bucket_cnt[e];
    int m0 = mt * 128;
    if (m0 >= cnt) return;
    int cl = min(cnt - m0, 128);
    if (tid < 128) {
        int idx = m0 + tid;
        rowArr[tid] = buckets[e * NPAIR + (idx < cnt ? idx : cnt - 1)];
    }
    __syncthreads();

    int r0 = tid >> 2, p0 = tid & 3;
    int g0 = (p0 - ((r0 >> 1) & 3)) & 3;
    const u16* gA0 = yb + (size_t)rowArr[r0] * 1024 + g0 * 8;
    const u16* gA1 = yb + (size_t)rowArr[r0 + 64] * 1024 + g0 * 8;
    const u16* gB0 = Wout_p + ((size_t)e << 20) + (((size_t)(nt * 32)) << 12) + tid * 8;
    const u16* gB1 = gB0 + 2048;

    int w = tid >> 6, lane = tid & 63, lm = lane & 15, g = lane >> 4;
    int mq = w >> 1, nq = w & 1;
    int offA[4], offB[4];
    frag_offsets(mq * 64, lm, g, offA);
    frag_offsets(nq * 64, lm, g, offB);
    f32x4 acc[4][4];
#pragma unroll
    for (int i = 0; i < 4; i++)
#pragma unroll
        for (int j = 0; j < 4; j++) acc[i][j] = 0;

    mfma_mainloop128(gA0, gA1, gB0, gB1, As, Bs, w, offA, offB, acc);

#pragma unroll
    for (int i = 0; i < 4; i++) {
#pragma unroll
        for (int reg = 0; reg < 4; reg++) {
            int lrow = mq * 64 + i * 16 + g * 4 + reg;
            if (lrow < cl) {
                int orow = rowArr[lrow];
#pragma unroll
                for (int j = 0; j < 4; j++) {
                    int col = nt * 128 + nq * 64 + j * 16 + lm;
                    Out[(size_t)orow * 1024 + col] = acc[i][j][reg];
                }
            }
        }
    }
}

// ---------------- Vb [bh][j][d] -> Vtb [bh][d][j] (bf16 transpose) ----------------
__global__ __launch_bounds__(256) void vtrans(
    const u16* __restrict__ Vb, u16* __restrict__ Vtb)
{
    __shared__ u16 t[64][72];
    int bh = blockIdx.x;
    int d0 = blockIdx.y * 64;
    int j0 = blockIdx.z * 64;
    int tid = threadIdx.x;
#pragma unroll
    for (int p = 0; p < 2; p++) {
        int c = tid + 256 * p;
        int jr = c >> 3, c8 = c & 7;
        *(bf16x8*)&t[jr][c8 * 8] =
            *(const bf16x8*)&Vb[((size_t)bh * 512 + j0 + jr) * 128 + d0 + c8 * 8];
    }
    __syncthreads();
#pragma unroll
    for (int p = 0; p < 2; p++) {
        int c = tid + 256 * p;
        int dr = c >> 3, j8 = c & 7;
        bf16x8 o;
#pragma unroll
        for (int k = 0; k < 8; k++) o[k] = (short)t[j8 * 8 + k][dr];
        *(bf16x8*)&Vtb[((size_t)bh * 128 + d0 + dr) * 512 + j0 + j8 * 8] = o;
    }
}

// ---------------- stick-breaking flash attention, MFMA ----------------
__global__ __launch_bounds__(256) void attn_kernel(
    const u16* __restrict__ Qb, const u16* __restrict__ Kb,
    const u16* __restrict__ Vtb, const float* __restrict__ gates,
    u16* __restrict__ yb)
{
    __shared__ __align__(16) u16 Qs[32 * 136];
    __shared__ __align__(16) u16 Ks[32 * 136];
    __shared__ __align__(16) u16 Vts[128 * 40];
    __shared__ __align__(16) float sw[32 * 36];
    __shared__ __align__(16) u16 wt[32 * 40];

    int combo = blockIdx.x;
    int b = combo >> 4, slot = (combo >> 3) & 1, h = combo & 7;
    int bh = b * 8 + h;
    const u16* Qbase = Qb  + ((size_t)combo << 16);
    const u16* Kbase = Kb  + ((size_t)bh << 16);
    const u16* Vbase = Vtb + ((size_t)bh << 16);

    int tid = threadIdx.x;
    int w = tid >> 6, lane = tid & 63, lm = lane & 15, g = lane >> 4;
    int mh = w >> 1, nh = w & 1, dsel = w & 1;
    int srow = tid >> 3, st = tid & 7;
    int rowlane = lane & 56;
    const float SCALE = 0.08838834764831845f;

    for (int seg = 0; seg < 2; seg++) {
        int it = seg ? (15 - blockIdx.y) : blockIdx.y;
        int i0 = it * 32;
        __syncthreads();
#pragma unroll
        for (int p = 0; p < 2; p++) {
            int c = tid + 256 * p;
            int r = c >> 4, c8 = c & 15;
            *(bf16x8*)&Qs[r * 136 + c8 * 8] =
                *(const bf16x8*)&Qbase[(size_t)(i0 + r) * 128 + c8 * 8];
        }
        f32x4 pacc[4];
#pragma unroll
        for (int q = 0; q < 4; q++) pacc[q] = 0;
        float running = 0.f;

        for (int jt = it; jt >= 0; jt--) {
            int j0 = jt * 32;
            __syncthreads();
#pragma unroll
            for (int p = 0; p < 2; p++) {
                int c = tid + 256 * p;
                int r = c >> 4, c8 = c & 15;
                *(bf16x8*)&Ks[r * 136 + c8 * 8] =
                    *(const bf16x8*)&Kbase[(size_t)(j0 + r) * 128 + c8 * 8];
            }
#pragma unroll
            for (int p = 0; p < 2; p++) {
                int c = tid + 256 * p;
                int d = c >> 2, j8 = c & 3;
                *(bf16x8*)&Vts[d * 40 + j8 * 8] =
                    *(const bf16x8*)&Vbase[(size_t)d * 512 + j0 + j8 * 8];
            }
            __syncthreads();
            f32x4 sacc = 0;
#pragma unroll
            for (int ks = 0; ks < 4; ks++) {
                bf16x8 aq = *(const bf16x8*)&Qs[(mh * 16 + lm) * 136 + ks * 32 + g * 8];
                bf16x8 bk = *(const bf16x8*)&Ks[(nh * 16 + lm) * 136 + ks * 32 + g * 8];
                sacc = __builtin_amdgcn_mfma_f32_16x16x32_bf16(aq, bk, sacc, 0, 0, 0);
            }
#pragma unroll
            for (int reg = 0; reg < 4; reg++)
                sw[(mh * 16 + g * 4 + reg) * 36 + nh * 16 + lm] = sacc[reg] * SCALE;
            __syncthreads();
            {
                float4 sv = *(const float4*)&sw[srow * 36 + st * 4];
                float sarr[4] = {sv.x, sv.y, sv.z, sv.w};
                int ig = i0 + srow;
                float lsig[4], lb[4];
#pragma unroll
                for (int c2 = 0; c2 < 4; c2++) {
                    int jg = j0 + st * 4 + c2;
                    float sc = sarr[c2];
                    float a  = fabsf(sc);
                    float tl = log1pf(__expf(-a));
                    lsig[c2] = (sc >= 0.f) ? -tl : sc - tl;
                    lb[c2]   = (jg <= ig) ? -(tl + fmaxf(sc, 0.f)) : 0.f;
                }
                float suf[4];
                suf[3] = 0.f;
                suf[2] = lb[3];
                suf[1] = lb[2] + lb[3];
                suf[0] = lb[1] + suf[1];
                float total = lb[0] + suf[0];
                float incl = total;
                float y1 = __shfl_down(incl, 1, 64); if (st < 7) incl += y1;
                float y2 = __shfl_down(incl, 2, 64); if (st < 6) incl += y2;
                float y4 = __shfl_down(incl, 4, 64); if (st < 4) incl += y4;
                float basev = (incl - total) + running;
                ushort4 wo;
                float wv;
                int jgc = j0 + st * 4;
                wv = (jgc + 0 <= ig) ? __expf(lsig[0] + suf[0] + basev) : 0.f; wo.x = f2bf(wv);
                wv = (jgc + 1 <= ig) ? __expf(lsig[1] + suf[1] + basev) : 0.f; wo.y = f2bf(wv);
                wv = (jgc + 2 <= ig) ? __expf(lsig[2] + suf[2] + basev) : 0.f; wo.z = f2bf(wv);
                wv = (jgc + 3 <= ig) ? __expf(lsig[3] + suf[3] + basev) : 0.f; wo.w = f2bf(wv);
                running += __shfl(incl, rowlane, 64);
                *(ushort4*)&wt[srow * 40 + st * 4] = wo;
            }
            __syncthreads();
            bf16x8 aw = *(const bf16x8*)&wt[(mh * 16 + lm) * 40 + g * 8];
#pragma unroll
            for (int q = 0; q < 4; q++) {
                int dt = q * 2 + dsel;
                bf16x8 bv8 = *(const bf16x8*)&Vts[(dt * 16 + lm) * 40 + g * 8];
                pacc[q] = __builtin_amdgcn_mfma_f32_16x16x32_bf16(aw, bv8, pacc[q], 0, 0, 0);
            }
        }
#pragma unroll
        for (int reg = 0; reg < 4; reg++) {
            int i = i0 + mh * 16 + g * 4 + reg;
            size_t pair = ((size_t)(b * 512 + i)) * 2 + slot;
            float gt = gates[pair];
#pragma unroll
            for (int q = 0; q < 4; q++) {
                int d = (q * 2 + dsel) * 16 + lm;
                yb[pair * 1024 + h * 128 + d] = f2bf(pacc[q][reg] * gt);
            }
        }
    }
}

// ---------------- combine pairs ----------------
__global__ __launch_bounds__(256) void combine_kernel(
    const float* __restrict__ tmp, float* __restrict__ out)
{
    int idx = blockIdx.x * 256 + threadIdx.x;
    int token = idx >> 8;
    int c4 = idx & 255;
    const float4* t4 = (const float4*)tmp;
    float4 a = t4[(size_t)(token * 2) * 256 + c4];
    float4 b = t4[(size_t)(token * 2 + 1) * 256 + c4];
    float4 r;
    r.x = a.x + b.x; r.y = a.y + b.y; r.z = a.z + b.z; r.w = a.w + b.w;
    ((float4*)out)[idx] = r;
}

extern "C" void kernel_launch(void* const* d_in, const int* in_sizes, int n_in,
                              void* d_out, int out_size, void* d_ws, size_t ws_size,
                              hipStream_t stream)
{
    const float* x     = (const float*)d_in[0];
    const float* Wg    = (const float*)d_in[1];
    const float* W_in  = (const float*)d_in[2];
    const float* W_out = (const float*)d_in[3];
    const float* Wk    = (const float*)d_in[4];
    const float* bk    = (const float*)d_in[5];
    const float* Wv    = (const float*)d_in[6];
    const float* bv    = (const float*)d_in[7];

    char* ws = (char*)d_ws;
    int*   bucket_cnt = (int*)ws;
    size_t off = 256;
    float* gates = (float*)(ws + off); off += (size_t)NPAIR * 4;
    int* buckets = (int*)(ws + off);   off += (size_t)E_ * NPAIR * 4;
    float* bkv   = (float*)(ws + off); off += 2048 * 4;
    float* probs = (float*)(ws + off); off += (size_t)NTOK * E_ * 4;
    int*   eass  = (int*)(ws + off);   off += (size_t)NPAIR * 4;
    off = (off + 255) & ~(size_t)255;
    u16* xb    = (u16*)(ws + off); off += (size_t)NTOK * C_ * 2;
    u16* Wkv_p = (u16*)(ws + off); off += (size_t)2048 * 1024 * 2;
    u16* wp    = (u16*)(ws + off); off += (size_t)E_ * 1024 * 1024 * 2;   // W_in_p then W_out_p
    u16* yb    = (u16*)(ws + off); off += (size_t)NPAIR * AH_ * 2;
    u16* Qbuf  = (u16*)(ws + off); off += (size_t)32 * 512 * 128 * 2;
    u16* Kbuf  = (u16*)(ws + off); off += (size_t)16 * 512 * 128 * 2;
    u16* Vbuf  = (u16*)(ws + off); off += (size_t)16 * 512 * 128 * 2;
    u16* Vtbuf = (u16*)(ws + off); off += (size_t)16 * 128 * 512 * 2;
    float* tmp = (float*)(ws + off); off += (size_t)NPAIR * AH_ * 4;

    gate_kernel<<<NTOK, 64, 0, stream>>>(x, Wg, xb, gates, probs, eass);
    route_kernel<<<1, 256, 0, stream>>>(probs, eass, bk, bv, bucket_cnt,
                                        buckets, bkv,
                                        (float*)d_out + (out_size - 1));
    pack_b<<<dim3(16, 16, 8), 256, 0, stream>>>(W_in, wp);
    pack_b<<<dim3(16, 16, 1), 256, 0, stream>>>(Wk, Wkv_p);
    pack_b<<<dim3(16, 16, 1), 256, 0, stream>>>(Wv, Wkv_p + ((size_t)1 << 20));

    // fused KV (dense, 128 blocks) + q (routed, 1024 logical blocks)
    gemm_fused<<<128 + 1024, 256, 0, stream>>>(xb, Wkv_p, bkv, wp, bucket_cnt,
                                               buckets, Kbuf, Vbuf, Qbuf);
    vtrans<<<dim3(16, 2, 8), 256, 0, stream>>>(Vbuf, Vtbuf);

    attn_kernel<<<dim3(32, 8), 256, 0, stream>>>(Qbuf, Kbuf, Vtbuf, gates, yb);

    pack_b<<<dim3(16, 16, 8), 256, 0, stream>>>(W_out, wp);   // wp reused after q-gemm
    gemm_wout<<<1024, 256, 0, stream>>>(yb, wp, bucket_cnt, buckets, tmp);

    combine_kernel<<<(NTOK * C_ / 4) / 256, 256, 0, stream>>>(tmp, (float*)d_out);
}

// Round 9
// 267.116 us; speedup vs baseline: 1.2152x; 1.1215x over previous
//
#include <hip/hip_runtime.h>
#include <cmath>

#define B_    2
#define T_    512
#define C_    1024
#define E_    8
#define NTOK  1024
#define NPAIR 2048
#define AH_   1024
#define NH_   8
#define HS_   128

typedef unsigned short u16;
typedef __attribute__((ext_vector_type(8))) short bf16x8;
typedef __attribute__((ext_vector_type(4))) float f32x4;

__device__ __forceinline__ u16 f2bf(float f) {
    union { float f; unsigned u; } v; v.f = f;
    unsigned r = v.u + 0x7fff + ((v.u >> 16) & 1);   // RNE
    return (u16)(r >> 16);
}

// ---------------- kernel 1: gate logits, top-2, x->bf16 (NO global atomics) ----------------
__global__ __launch_bounds__(64) void gate_kernel(
    const float* __restrict__ x, const float* __restrict__ Wg,
    u16* __restrict__ xb, float* __restrict__ gates,
    float* __restrict__ probs, int* __restrict__ eass)
{
    int token = blockIdx.x;
    int lane  = threadIdx.x;
    const float* xr = x + (size_t)token * C_;
    u16* xbr = xb + (size_t)token * C_;
    float acc[E_];
#pragma unroll
    for (int e = 0; e < E_; e++) acc[e] = 0.f;
    for (int c = lane; c < C_; c += 64) {
        float xv = xr[c];
        xbr[c] = f2bf(xv);
        const float* wr = Wg + c * E_;
#pragma unroll
        for (int e = 0; e < E_; e++) acc[e] += xv * wr[e];
    }
#pragma unroll
    for (int e = 0; e < E_; e++) {
        float v = acc[e];
        v += __shfl_xor(v, 32); v += __shfl_xor(v, 16); v += __shfl_xor(v, 8);
        v += __shfl_xor(v, 4);  v += __shfl_xor(v, 2);  v += __shfl_xor(v, 1);
        acc[e] = v;
    }
    if (lane == 0) {
        int i0 = 0; float v0 = acc[0];
        for (int e = 1; e < E_; e++) if (acc[e] > v0) { v0 = acc[e]; i0 = e; }
        int i1 = -1; float v1 = -3.4e38f;
        for (int e = 0; e < E_; e++) if (e != i0 && acc[e] > v1) { v1 = acc[e]; i1 = e; }
        float e1  = __expf(v1 - v0);
        float inv = 1.f / (1.f + e1);
        gates[token * 2 + 0] = inv;
        gates[token * 2 + 1] = e1 * inv;
        float s = 0.f; float pe[E_];
        for (int e = 0; e < E_; e++) { pe[e] = __expf(acc[e] - v0); s += pe[e]; }
        float sinv = 1.f / s;
        for (int e = 0; e < E_; e++) probs[token * E_ + e] = pe[e] * sinv;
        eass[token * 2 + 0] = i0;
        eass[token * 2 + 1] = i1;
    }
}

// ---------------- kernel 1b: aux-loss reduce + bucket build (single block) ----------------
__global__ __launch_bounds__(256) void route_kernel(
    const float* __restrict__ probs, const int* __restrict__ eass,
    const float* __restrict__ bk, const float* __restrict__ bv,
    int* __restrict__ bucket_cnt, int* __restrict__ buckets,
    float* __restrict__ bkv, float* __restrict__ aux_out)
{
    __shared__ float red[256][17];
    __shared__ int lcnt[E_];
    int tid = threadIdx.x;
    for (int i = tid; i < 1024; i += 256) {
        bkv[i] = bk[i];
        bkv[i + 1024] = bv[i];
    }
    float ps[E_], fc[E_];
#pragma unroll
    for (int e = 0; e < E_; e++) { ps[e] = 0.f; fc[e] = 0.f; }
    for (int k = 0; k < 4; k++) {
        int row = tid + k * 256;
#pragma unroll
        for (int e = 0; e < E_; e++) ps[e] += probs[row * E_ + e];
    }
    for (int k = 0; k < 8; k++) {
        int i = tid + k * 256;
        int ea = eass[i];
#pragma unroll
        for (int e = 0; e < E_; e++) fc[e] += (ea == e) ? 1.f : 0.f;
    }
#pragma unroll
    for (int e = 0; e < E_; e++) { red[tid][e] = ps[e]; red[tid][8 + e] = fc[e]; }
    if (tid < E_) lcnt[tid] = 0;
    __syncthreads();
    for (int s = 128; s > 0; s >>= 1) {
        if (tid < s)
#pragma unroll
            for (int j = 0; j < 16; j++) red[tid][j] += red[tid + s][j];
        __syncthreads();
    }
    if (tid == 0) {
        float s = 0.f;
        for (int e = 0; e < E_; e++)
            s += (red[0][e] * (1.f / 1024.f)) * (red[0][8 + e] * (1.f / 1024.f));
        aux_out[0] = (float)E_ * s;
    }
    for (int k = 0; k < 8; k++) {
        int i = tid + k * 256;
        int ea = eass[i];
        int pos = atomicAdd(&lcnt[ea], 1);
        buckets[ea * NPAIR + pos] = i;
    }
    __syncthreads();
    if (tid < E_) bucket_cnt[tid] = lcnt[tid];
}

// ---------------- pack fp32 [k][n] -> bf16 B-tiles (fragment-contiguous, swizzle baked) ----
// u16 index: (nt*32+ks)*4096 + n_loc*32 + p*8 + j
// content:   W[(ks*32 + g*8 + j)*1024 + nt*128 + n_loc],  g=(p-((n_loc>>1)&3))&3
__global__ __launch_bounds__(256) void pack_b(
    const float* __restrict__ src, u16* __restrict__ dst)
{
    __shared__ float t[64][65];          // t[k_rel][n_rel]
    src += (size_t)blockIdx.z << 20;
    dst += (size_t)blockIdx.z << 20;
    int k0 = blockIdx.y * 64, n0 = blockIdx.x * 64;
    int tid = threadIdx.x;
#pragma unroll
    for (int p = 0; p < 4; p++) {
        int e4 = tid + 256 * p;          // 1024 float4 = 64 k-rows x 16 float4
        int r = e4 >> 4, c4 = e4 & 15;
        float4 v = *(const float4*)&src[(size_t)(k0 + r) * 1024 + n0 + c4 * 4];
        t[r][c4 * 4 + 0] = v.x; t[r][c4 * 4 + 1] = v.y;
        t[r][c4 * 4 + 2] = v.z; t[r][c4 * 4 + 3] = v.w;
    }
    __syncthreads();
    int c = tid & 63, ks_rel = (tid >> 6) & 1, ph = tid >> 7;
    int n_glob = n0 + c, nt = n_glob >> 7, n_loc = n_glob & 127;
    int ks = (k0 >> 5) + ks_rel;
    u16* ob = dst + (((size_t)(nt * 32 + ks)) << 12) + n_loc * 32;
#pragma unroll
    for (int pp = 0; pp < 2; pp++) {
        int p = ph * 2 + pp;
        int g = (p - ((n_loc >> 1) & 3)) & 3;
        int kb = ks_rel * 32 + g * 8;
        ushort4 o1, o2;
        o1.x = f2bf(t[kb + 0][c]); o1.y = f2bf(t[kb + 1][c]);
        o1.z = f2bf(t[kb + 2][c]); o1.w = f2bf(t[kb + 3][c]);
        o2.x = f2bf(t[kb + 4][c]); o2.y = f2bf(t[kb + 5][c]);
        o2.z = f2bf(t[kb + 6][c]); o2.w = f2bf(t[kb + 7][c]);
        *(ushort4*)&ob[p * 8]     = o1;
        *(ushort4*)&ob[p * 8 + 4] = o2;
    }
}

// ---------------- register-direct MFMA mainloop: wave = 16 rows x 128 cols ----------------
// No LDS, no barriers. A-frag: 16B/lane from row-major A (lane row=lm, chunk g).
// B-frag j: 16B/lane from packed B (perfectly coalesced 1KB/instr per frag).
// Depth-2 register double-buffer; compiler handles vmcnt pipelining.
__device__ __forceinline__ void mfma_strip_loop(
    const u16* __restrict__ Aptr,      // per-lane: A + row*1024 + g*8
    const u16* __restrict__ Bptr,      // per-lane: packed-B tile + n_loc*32 + swz*8
    f32x4 acc[8])
{
    bf16x8 abuf[2];
    bf16x8 bbuf[2][8];
    abuf[0] = *(const bf16x8*)(Aptr);
    abuf[1] = *(const bf16x8*)(Aptr + 32);
#pragma unroll
    for (int j = 0; j < 8; j++) {
        bbuf[0][j] = *(const bf16x8*)(Bptr + j * 512);
        bbuf[1][j] = *(const bf16x8*)(Bptr + 4096 + j * 512);
    }
#pragma unroll
    for (int k = 0; k < 32; k++) {
        int cur = k & 1;
        bf16x8 a = abuf[cur];
        bf16x8 b[8];
#pragma unroll
        for (int j = 0; j < 8; j++) b[j] = bbuf[cur][j];
        if (k < 30) {
            abuf[cur] = *(const bf16x8*)(Aptr + (size_t)(k + 2) * 32);
#pragma unroll
            for (int j = 0; j < 8; j++)
                bbuf[cur][j] = *(const bf16x8*)(Bptr + (size_t)(k + 2) * 4096 + j * 512);
        }
#pragma unroll
        for (int j = 0; j < 8; j++)
            acc[j] = __builtin_amdgcn_mfma_f32_16x16x32_bf16(a, b[j], acc[j], 0, 0, 0);
    }
}

// ---------------- fused KV (dense) + q (routed) GEMM, wave-strip, registers only --------
// bx < 256: KV  (mt=bx&15, nt=bx>>4; M=1024 N=2048) -> Kb/Vb (+bias)
// bx >= 256: q  (b2=bx-256: mt=b2>>6, e=(b2&63)>>3, nt=b2&7) -> Qb
__global__ __launch_bounds__(256) void gemm_fused(
    const u16* __restrict__ xb, const u16* __restrict__ Wkv_p,
    const float* __restrict__ bkv, const u16* __restrict__ Win_p,
    const int* __restrict__ bucket_cnt, const int* __restrict__ buckets,
    u16* __restrict__ Kb, u16* __restrict__ Vb, u16* __restrict__ Qb)
{
    int bx = blockIdx.x;
    int tid = threadIdx.x;
    int w = tid >> 6, lane = tid & 63, lm = lane & 15, g = lane >> 4;
    bool isKV = bx < 256;
    int e = 0, mt, nt, cnt;
    const u16* Wp;
    if (isKV) {
        mt = bx & 15; nt = bx >> 4; cnt = NTOK; Wp = Wkv_p;
    } else {
        int b2 = bx - 256;
        mt = b2 >> 6; e = (b2 & 63) >> 3; nt = b2 & 7;
        cnt = bucket_cnt[e];
        Wp = Win_p + ((size_t)e << 20);
    }
    int m0 = mt * 64;
    if (m0 >= cnt) return;
    int strip = m0 + w * 16;

    // A row (for loading) and D rows (for storing)
    int arow, drow[4];
    if (isKV) {
        arow = strip + lm;
#pragma unroll
        for (int r = 0; r < 4; r++) drow[r] = strip + g * 4 + r;
    } else {
        int ai = strip + lm;
        arow = buckets[e * NPAIR + (ai < cnt ? ai : cnt - 1)] >> 1;   // token
#pragma unroll
        for (int r = 0; r < 4; r++) {
            int di = strip + g * 4 + r;
            drow[r] = (di < cnt) ? buckets[e * NPAIR + di] : -1;      // pair
        }
    }
    const u16* Aptr = xb + (size_t)arow * 1024 + g * 8;
    int n_loc0 = lm;   // frag j adds j*16
    // per-lane B pointer for frag j: Btile + (j*16+lm)*32 + swz*8; fold j via +j*512
    int swz0 = (g + ((n_loc0 >> 1) & 3)) & 3;   // (j*16+lm)>>1 &3 == (lm>>1)&3
    const u16* Bptr = Wp + (((size_t)(nt * 32)) << 12) + n_loc0 * 32 + swz0 * 8;

    f32x4 acc[8];
#pragma unroll
    for (int j = 0; j < 8; j++) acc[j] = 0;

    mfma_strip_loop(Aptr, Bptr, acc);

    // epilogue: D row (within frag) = g*4+reg, col = nt*128 + j*16 + lm
#pragma unroll
    for (int reg = 0; reg < 4; reg++) {
        int di = strip + g * 4 + reg;
        if (isKV || di < cnt) {
            int orow = isKV ? drow[reg] : drow[reg];
            if (!isKV && orow < 0) continue;
#pragma unroll
            for (int j = 0; j < 8; j++) {
                int col = nt * 128 + j * 16 + lm;
                float v = acc[j][reg];
                if (isKV) {
                    v += bkv[col];
                    int tb = orow >> 9, tj = orow & 511;
                    int cc = col & 1023;
                    int hh = cc >> 7, dd = cc & 127;
                    u16* dst = (col < 1024) ? Kb : Vb;
                    dst[(((size_t)(tb * 8 + hh) * 512 + tj) << 7) + dd] = f2bf(v);
                } else {
                    int pb = orow >> 10, pi = (orow >> 1) & 511, ps = orow & 1;
                    int hh = col >> 7, dd = col & 127;
                    Qb[((((size_t)(pb * 16 + ps * 8 + hh)) * 512 + pi) << 7) + dd] = f2bf(v);
                }
            }
        }
    }
}

// ---------------- W_out routed GEMM, wave-strip, fp32 out ----------------
// grid 2048: mt=bx>>6 (0..31), e=(bx&63)>>3, nt=bx&7
__global__ __launch_bounds__(256) void gemm_wout(
    const u16* __restrict__ yb, const u16* __restrict__ Wout_p,
    const int* __restrict__ bucket_cnt, const int* __restrict__ buckets,
    float* __restrict__ Out)
{
    int bx = blockIdx.x;
    int tid = threadIdx.x;
    int w = tid >> 6, lane = tid & 63, lm = lane & 15, g = lane >> 4;
    int mt = bx >> 6, e = (bx & 63) >> 3, nt = bx & 7;
    int cnt = bucket_cnt[e];
    int m0 = mt * 64;
    if (m0 >= cnt) return;
    int strip = m0 + w * 16;

    int ai = strip + lm;
    int arow = buckets[e * NPAIR + (ai < cnt ? ai : cnt - 1)];
    int drow[4];
#pragma unroll
    for (int r = 0; r < 4; r++) {
        int di = strip + g * 4 + r;
        drow[r] = (di < cnt) ? buckets[e * NPAIR + di] : -1;
    }
    const u16* Aptr = yb + (size_t)arow * 1024 + g * 8;
    int swz0 = (g + ((lm >> 1) & 3)) & 3;
    const u16* Bptr = Wout_p + ((size_t)e << 20) + (((size_t)(nt * 32)) << 12)
                      + lm * 32 + swz0 * 8;

    f32x4 acc[8];
#pragma unroll
    for (int j = 0; j < 8; j++) acc[j] = 0;

    mfma_strip_loop(Aptr, Bptr, acc);

#pragma unroll
    for (int reg = 0; reg < 4; reg++) {
        int orow = drow[reg];
        if (orow >= 0) {
#pragma unroll
            for (int j = 0; j < 8; j++) {
                int col = nt * 128 + j * 16 + lm;
                Out[(size_t)orow * 1024 + col] = acc[j][reg];
            }
        }
    }
}

// ---------------- Vb [bh][j][d] -> Vtb [bh][d][j] (bf16 transpose) ----------------
__global__ __launch_bounds__(256) void vtrans(
    const u16* __restrict__ Vb, u16* __restrict__ Vtb)
{
    __shared__ u16 t[64][72];
    int bh = blockIdx.x;
    int d0 = blockIdx.y * 64;
    int j0 = blockIdx.z * 64;
    int tid = threadIdx.x;
#pragma unroll
    for (int p = 0; p < 2; p++) {
        int c = tid + 256 * p;
        int jr = c >> 3, c8 = c & 7;
        *(bf16x8*)&t[jr][c8 * 8] =
            *(const bf16x8*)&Vb[((size_t)bh * 512 + j0 + jr) * 128 + d0 + c8 * 8];
    }
    __syncthreads();
#pragma unroll
    for (int p = 0; p < 2; p++) {
        int c = tid + 256 * p;
        int dr = c >> 3, j8 = c & 7;
        bf16x8 o;
#pragma unroll
        for (int k = 0; k < 8; k++) o[k] = (short)t[j8 * 8 + k][dr];
        *(bf16x8*)&Vtb[((size_t)bh * 128 + d0 + dr) * 512 + j0 + j8 * 8] = o;
    }
}

// ---------------- stick-breaking flash attention, MFMA ----------------
__global__ __launch_bounds__(256) void attn_kernel(
    const u16* __restrict__ Qb, const u16* __restrict__ Kb,
    const u16* __restrict__ Vtb, const float* __restrict__ gates,
    u16* __restrict__ yb)
{
    __shared__ __align__(16) u16 Qs[32 * 136];
    __shared__ __align__(16) u16 Ks[32 * 136];
    __shared__ __align__(16) u16 Vts[128 * 40];
    __shared__ __align__(16) float sw[32 * 36];
    __shared__ __align__(16) u16 wt[32 * 40];

    int combo = blockIdx.x;
    int b = combo >> 4, slot = (combo >> 3) & 1, h = combo & 7;
    int bh = b * 8 + h;
    const u16* Qbase = Qb  + ((size_t)combo << 16);
    const u16* Kbase = Kb  + ((size_t)bh << 16);
    const u16* Vbase = Vtb + ((size_t)bh << 16);

    int tid = threadIdx.x;
    int w = tid >> 6, lane = tid & 63, lm = lane & 15, g = lane >> 4;
    int mh = w >> 1, nh = w & 1, dsel = w & 1;
    int srow = tid >> 3, st = tid & 7;
    int rowlane = lane & 56;
    const float SCALE = 0.08838834764831845f;

    for (int seg = 0; seg < 2; seg++) {
        int it = seg ? (15 - blockIdx.y) : blockIdx.y;
        int i0 = it * 32;
        __syncthreads();
#pragma unroll
        for (int p = 0; p < 2; p++) {
            int c = tid + 256 * p;
            int r = c >> 4, c8 = c & 15;
            *(bf16x8*)&Qs[r * 136 + c8 * 8] =
                *(const bf16x8*)&Qbase[(size_t)(i0 + r) * 128 + c8 * 8];
        }
        f32x4 pacc[4];
#pragma unroll
        for (int q = 0; q < 4; q++) pacc[q] = 0;
        float running = 0.f;

        for (int jt = it; jt >= 0; jt--) {
            int j0 = jt * 32;
            __syncthreads();
#pragma unroll
            for (int p = 0; p < 2; p++) {
                int c = tid + 256 * p;
                int r = c >> 4, c8 = c & 15;
                *(bf16x8*)&Ks[r * 136 + c8 * 8] =
                    *(const bf16x8*)&Kbase[(size_t)(j0 + r) * 128 + c8 * 8];
            }
#pragma unroll
            for (int p = 0; p < 2; p++) {
                int c = tid + 256 * p;
                int d = c >> 2, j8 = c & 3;
                *(bf16x8*)&Vts[d * 40 + j8 * 8] =
                    *(const bf16x8*)&Vbase[(size_t)d * 512 + j0 + j8 * 8];
            }
            __syncthreads();
            f32x4 sacc = 0;
#pragma unroll
            for (int ks = 0; ks < 4; ks++) {
                bf16x8 aq = *(const bf16x8*)&Qs[(mh * 16 + lm) * 136 + ks * 32 + g * 8];
                bf16x8 bk = *(const bf16x8*)&Ks[(nh * 16 + lm) * 136 + ks * 32 + g * 8];
                sacc = __builtin_amdgcn_mfma_f32_16x16x32_bf16(aq, bk, sacc, 0, 0, 0);
            }
#pragma unroll
            for (int reg = 0; reg < 4; reg++)
                sw[(mh * 16 + g * 4 + reg) * 36 + nh * 16 + lm] = sacc[reg] * SCALE;
            __syncthreads();
            {
                float4 sv = *(const float4*)&sw[srow * 36 + st * 4];
                float sarr[4] = {sv.x, sv.y, sv.z, sv.w};
                int ig = i0 + srow;
                float lsig[4], lb[4];
#pragma unroll
                for (int c2 = 0; c2 < 4; c2++) {
                    int jg = j0 + st * 4 + c2;
                    float sc = sarr[c2];
                    float a  = fabsf(sc);
                    float tl = log1pf(__expf(-a));
                    lsig[c2] = (sc >= 0.f) ? -tl : sc - tl;
                    lb[c2]   = (jg <= ig) ? -(tl + fmaxf(sc, 0.f)) : 0.f;
                }
                float suf[4];
                suf[3] = 0.f;
                suf[2] = lb[3];
                suf[1] = lb[2] + lb[3];
                suf[0] = lb[1] + suf[1];
                float total = lb[0] + suf[0];
                float incl = total;
                float y1 = __shfl_down(incl, 1, 64); if (st < 7) incl += y1;
                float y2 = __shfl_down(incl, 2, 64); if (st < 6) incl += y2;
                float y4 = __shfl_down(incl, 4, 64); if (st < 4) incl += y4;
                float basev = (incl - total) + running;
                ushort4 wo;
                float wv;
                int jgc = j0 + st * 4;
                wv = (jgc + 0 <= ig) ? __expf(lsig[0] + suf[0] + basev) : 0.f; wo.x = f2bf(wv);
                wv = (jgc + 1 <= ig) ? __expf(lsig[1] + suf[1] + basev) : 0.f; wo.y = f2bf(wv);
                wv = (jgc + 2 <= ig) ? __expf(lsig[2] + suf[2] + basev) : 0.f; wo.z = f2bf(wv);
                wv = (jgc + 3 <= ig) ? __expf(lsig[3] + suf[3] + basev) : 0.f; wo.w = f2bf(wv);
                running += __shfl(incl, rowlane, 64);
                *(ushort4*)&wt[srow * 40 + st * 4] = wo;
            }
            __syncthreads();
            bf16x8 aw = *(const bf16x8*)&wt[(mh * 16 + lm) * 40 + g * 8];
#pragma unroll
            for (int q = 0; q < 4; q++) {
                int dt = q * 2 + dsel;
                bf16x8 bv8 = *(const bf16x8*)&Vts[(dt * 16 + lm) * 40 + g * 8];
                pacc[q] = __builtin_amdgcn_mfma_f32_16x16x32_bf16(aw, bv8, pacc[q], 0, 0, 0);
            }
        }
#pragma unroll
        for (int reg = 0; reg < 4; reg++) {
            int i = i0 + mh * 16 + g * 4 + reg;
            size_t pair = ((size_t)(b * 512 + i)) * 2 + slot;
            float gt = gates[pair];
#pragma unroll
            for (int q = 0; q < 4; q++) {
                int d = (q * 2 + dsel) * 16 + lm;
                yb[pair * 1024 + h * 128 + d] = f2bf(pacc[q][reg] * gt);
            }
        }
    }
}

// ---------------- combine pairs ----------------
__global__ __launch_bounds__(256) void combine_kernel(
    const float* __restrict__ tmp, float* __restrict__ out)
{
    int idx = blockIdx.x * 256 + threadIdx.x;
    int token = idx >> 8;
    int c4 = idx & 255;
    const float4* t4 = (const float4*)tmp;
    float4 a = t4[(size_t)(token * 2) * 256 + c4];
    float4 b = t4[(size_t)(token * 2 + 1) * 256 + c4];
    float4 r;
    r.x = a.x + b.x; r.y = a.y + b.y; r.z = a.z + b.z; r.w = a.w + b.w;
    ((float4*)out)[idx] = r;
}

extern "C" void kernel_launch(void* const* d_in, const int* in_sizes, int n_in,
                              void* d_out, int out_size, void* d_ws, size_t ws_size,
                              hipStream_t stream)
{
    const float* x     = (const float*)d_in[0];
    const float* Wg    = (const float*)d_in[1];
    const float* W_in  = (const float*)d_in[2];
    const float* W_out = (const float*)d_in[3];
    const float* Wk    = (const float*)d_in[4];
    const float* bk    = (const float*)d_in[5];
    const float* Wv    = (const float*)d_in[6];
    const float* bv    = (const float*)d_in[7];

    char* ws = (char*)d_ws;
    int*   bucket_cnt = (int*)ws;
    size_t off = 256;
    float* gates = (float*)(ws + off); off += (size_t)NPAIR * 4;
    int* buckets = (int*)(ws + off);   off += (size_t)E_ * NPAIR * 4;
    float* bkv   = (float*)(ws + off); off += 2048 * 4;
    float* probs = (float*)(ws + off); off += (size_t)NTOK * E_ * 4;
    int*   eass  = (int*)(ws + off);   off += (size_t)NPAIR * 4;
    off = (off + 255) & ~(size_t)255;
    u16* xb    = (u16*)(ws + off); off += (size_t)NTOK * C_ * 2;
    u16* Wkv_p = (u16*)(ws + off); off += (size_t)2048 * 1024 * 2;
    u16* wp    = (u16*)(ws + off); off += (size_t)E_ * 1024 * 1024 * 2;   // W_in_p then W_out_p
    u16* yb    = (u16*)(ws + off); off += (size_t)NPAIR * AH_ * 2;
    u16* Qbuf  = (u16*)(ws + off); off += (size_t)32 * 512 * 128 * 2;
    u16* Kbuf  = (u16*)(ws + off); off += (size_t)16 * 512 * 128 * 2;
    u16* Vbuf  = (u16*)(ws + off); off += (size_t)16 * 512 * 128 * 2;
    u16* Vtbuf = (u16*)(ws + off); off += (size_t)16 * 128 * 512 * 2;
    float* tmp = (float*)(ws + off); off += (size_t)NPAIR * AH_ * 4;

    gate_kernel<<<NTOK, 64, 0, stream>>>(x, Wg, xb, gates, probs, eass);
    route_kernel<<<1, 256, 0, stream>>>(probs, eass, bk, bv, bucket_cnt,
                                        buckets, bkv,
                                        (float*)d_out + (out_size - 1));
    pack_b<<<dim3(16, 16, 8), 256, 0, stream>>>(W_in, wp);
    pack_b<<<dim3(16, 16, 1), 256, 0, stream>>>(Wk, Wkv_p);
    pack_b<<<dim3(16, 16, 1), 256, 0, stream>>>(Wv, Wkv_p + ((size_t)1 << 20));

    // fused KV (256 blocks) + q (2048 logical blocks, ~256 active)
    gemm_fused<<<256 + 2048, 256, 0, stream>>>(xb, Wkv_p, bkv, wp, bucket_cnt,
                                               buckets, Kbuf, Vbuf, Qbuf);
    vtrans<<<dim3(16, 2, 8), 256, 0, stream>>>(Vbuf, Vtbuf);

    attn_kernel<<<dim3(32, 8), 256, 0, stream>>>(Qbuf, Kbuf, Vtbuf, gates, yb);

    pack_b<<<dim3(16, 16, 8), 256, 0, stream>>>(W_out, wp);   // wp reused after q-gemm
    gemm_wout<<<2048, 256, 0, stream>>>(yb, wp, bucket_cnt, buckets, tmp);

    combine_kernel<<<(NTOK * C_ / 4) / 256, 256, 0, stream>>>(tmp, (float*)d_out);
}